// Round 1
// baseline (131664.441 us; speedup 1.0000x reference)
//
#include <hip/hip_runtime.h>
#include <math.h>

#define Bsz 256
#define Tsz 512
#define Hsz 1024

__device__ __forceinline__ float sigm(float v)   { return 1.0f / (1.0f + expf(-v)); }
__device__ __forceinline__ float tanh_f(float v) { float e = expf(2.0f * v); return 1.0f - 2.0f / (e + 1.0f); }

// ---------------------------------------------------------------------------
// Phase A: layer-1 LSTM cell for one timestep.
// gates1[b][g*H+n] = sum_k h1_in[k][b] * W_hh1[g*H+n][k]  + x[b][t]*W_ih1[g*H+n] + b1
// State layout is TRANSPOSED: h/c stored as [H][B] (n-major) so that
//   - GEMM B-operand staging reads are coalesced along b
//   - cell-state reads/writes are coalesced float4 along b
// Block: 256 threads = 16 n-threads x 16 b-threads; tile 16 n x 64 b;
// each thread owns 1 n x 4 consecutive b, all 4 gates (16 fp32 accumulators).
// Grid: (64 n-tiles, 4 b-tiles) = 256 blocks.
// ---------------------------------------------------------------------------
__global__ __launch_bounds__(256) void phaseA(
    const float* __restrict__ h1_in, float* __restrict__ h1_out,
    float* __restrict__ c1, const float* __restrict__ x,
    const float* __restrict__ W_ih1, const float* __restrict__ W_hh1,
    const float* __restrict__ b_ih1, const float* __restrict__ b_hh1, int t)
{
    __shared__ float Ws[64 * 36];   // 64 weight rows x 32 k, padded stride 36 (16B-aligned rows, conflict-free)
    __shared__ float Hs[32 * 64];   // 32 k x 64 b

    const int tid   = threadIdx.x;
    const int tb    = tid & 15;     // b-thread: owns b = bBase + 4*tb .. +3
    const int tn    = tid >> 4;     // n-thread: owns n = nBase + tn
    const int nBase = blockIdx.x << 4;
    const int bBase = blockIdx.y << 6;
    const int n     = nBase + tn;

    float acc[4][4];
    #pragma unroll
    for (int g = 0; g < 4; ++g)
        #pragma unroll
        for (int bb = 0; bb < 4; ++bb) acc[g][bb] = 0.0f;

    for (int k0 = 0; k0 < Hsz; k0 += 32) {
        // stage 64 weight rows (4 gates x 16 n), float4
        #pragma unroll
        for (int i4 = tid; i4 < 512; i4 += 256) {
            int r = i4 >> 3, k4 = (i4 & 7) << 2;
            int g = r >> 4, nn = r & 15;
            const float4 wv = *(const float4*)&W_hh1[(size_t)(g * Hsz + nBase + nn) * Hsz + k0 + k4];
            *(float4*)&Ws[r * 36 + k4] = wv;
        }
        // stage h tile [32 k][64 b], float4
        #pragma unroll
        for (int i4 = tid; i4 < 512; i4 += 256) {
            int kk = i4 >> 4, b4 = (i4 & 15) << 2;
            const float4 hv = *(const float4*)&h1_in[(k0 + kk) * Bsz + bBase + b4];
            *(float4*)&Hs[kk * 64 + b4] = hv;
        }
        __syncthreads();
        #pragma unroll
        for (int kk = 0; kk < 32; ++kk) {
            const float4 hv = *(const float4*)&Hs[kk * 64 + (tb << 2)];
            #pragma unroll
            for (int g = 0; g < 4; ++g) {
                const float wv = Ws[(g * 16 + tn) * 36 + kk];
                acc[g][0] += wv * hv.x; acc[g][1] += wv * hv.y;
                acc[g][2] += wv * hv.z; acc[g][3] += wv * hv.w;
            }
        }
        __syncthreads();
    }

    // epilogue: x outer-product term + biases + cell update
    float wih[4], bsum[4];
    #pragma unroll
    for (int g = 0; g < 4; ++g) {
        int j = g * Hsz + n;
        wih[g]  = W_ih1[j];
        bsum[g] = b_ih1[j] + b_hh1[j];
    }
    const int bOff = bBase + (tb << 2);
    float4 cold = *(const float4*)&c1[n * Bsz + bOff];
    float cprev[4] = {cold.x, cold.y, cold.z, cold.w};
    float cn[4], hn[4];
    #pragma unroll
    for (int bb = 0; bb < 4; ++bb) {
        float xv = x[(size_t)(bOff + bb) * Tsz + t];
        float gi = acc[0][bb] + xv * wih[0] + bsum[0];
        float gf = acc[1][bb] + xv * wih[1] + bsum[1];
        float gg = acc[2][bb] + xv * wih[2] + bsum[2];
        float go = acc[3][bb] + xv * wih[3] + bsum[3];
        float c_ = sigm(gf) * cprev[bb] + sigm(gi) * tanh_f(gg);
        cn[bb] = c_;
        hn[bb] = sigm(go) * tanh_f(c_);
    }
    *(float4*)&c1[n * Bsz + bOff]     = make_float4(cn[0], cn[1], cn[2], cn[3]);
    *(float4*)&h1_out[n * Bsz + bOff] = make_float4(hn[0], hn[1], hn[2], hn[3]);
}

// ---------------------------------------------------------------------------
// Phase B: layer-2 LSTM cell + output projection for one timestep.
// gates2 = h1 . W_ih2^T + h2 . W_hh2^T + b2   (virtual K = 2048)
// out[b][t] = sum_n h2_new[n][b] * W_out[n] + b_out  (b_out pre-filled by out_init;
// partials LDS-reduced over the block's 16 n, then one atomicAdd per (block, b)).
// ---------------------------------------------------------------------------
__global__ __launch_bounds__(256) void phaseB(
    const float* __restrict__ h1, const float* __restrict__ h2_in,
    float* __restrict__ h2_out, float* __restrict__ c2,
    const float* __restrict__ W_ih2, const float* __restrict__ W_hh2,
    const float* __restrict__ b_ih2, const float* __restrict__ b_hh2,
    const float* __restrict__ W_out, float* __restrict__ out, int t)
{
    __shared__ float Ws[64 * 36];
    __shared__ float Hs[32 * 64];
    __shared__ float red[256 * 4];

    const int tid   = threadIdx.x;
    const int tb    = tid & 15;
    const int tn    = tid >> 4;
    const int nBase = blockIdx.x << 4;
    const int bBase = blockIdx.y << 6;
    const int n     = nBase + tn;

    float acc[4][4];
    #pragma unroll
    for (int g = 0; g < 4; ++g)
        #pragma unroll
        for (int bb = 0; bb < 4; ++bb) acc[g][bb] = 0.0f;

    for (int kt = 0; kt < 64; ++kt) {
        const float* Wsrc = (kt < 32) ? W_ih2 : W_hh2;
        const float* hsrc = (kt < 32) ? h1 : h2_in;
        const int k0 = (kt & 31) << 5;

        #pragma unroll
        for (int i4 = tid; i4 < 512; i4 += 256) {
            int r = i4 >> 3, k4 = (i4 & 7) << 2;
            int g = r >> 4, nn = r & 15;
            const float4 wv = *(const float4*)&Wsrc[(size_t)(g * Hsz + nBase + nn) * Hsz + k0 + k4];
            *(float4*)&Ws[r * 36 + k4] = wv;
        }
        #pragma unroll
        for (int i4 = tid; i4 < 512; i4 += 256) {
            int kk = i4 >> 4, b4 = (i4 & 15) << 2;
            const float4 hv = *(const float4*)&hsrc[(k0 + kk) * Bsz + bBase + b4];
            *(float4*)&Hs[kk * 64 + b4] = hv;
        }
        __syncthreads();
        #pragma unroll
        for (int kk = 0; kk < 32; ++kk) {
            const float4 hv = *(const float4*)&Hs[kk * 64 + (tb << 2)];
            #pragma unroll
            for (int g = 0; g < 4; ++g) {
                const float wv = Ws[(g * 16 + tn) * 36 + kk];
                acc[g][0] += wv * hv.x; acc[g][1] += wv * hv.y;
                acc[g][2] += wv * hv.z; acc[g][3] += wv * hv.w;
            }
        }
        __syncthreads();
    }

    float bsum[4];
    #pragma unroll
    for (int g = 0; g < 4; ++g) {
        int j = g * Hsz + n;
        bsum[g] = b_ih2[j] + b_hh2[j];
    }
    const int bOff = bBase + (tb << 2);
    float4 cold = *(const float4*)&c2[n * Bsz + bOff];
    float cprev[4] = {cold.x, cold.y, cold.z, cold.w};
    const float wo = W_out[n];
    float cn[4], hn[4];
    #pragma unroll
    for (int bb = 0; bb < 4; ++bb) {
        float gi = acc[0][bb] + bsum[0];
        float gf = acc[1][bb] + bsum[1];
        float gg = acc[2][bb] + bsum[2];
        float go = acc[3][bb] + bsum[3];
        float c_ = sigm(gf) * cprev[bb] + sigm(gi) * tanh_f(gg);
        cn[bb] = c_;
        hn[bb] = sigm(go) * tanh_f(c_);
        red[(tid << 2) + bb] = hn[bb] * wo;
    }
    *(float4*)&c2[n * Bsz + bOff]     = make_float4(cn[0], cn[1], cn[2], cn[3]);
    *(float4*)&h2_out[n * Bsz + bOff] = make_float4(hn[0], hn[1], hn[2], hn[3]);

    __syncthreads();
    if (tn == 0) {
        #pragma unroll
        for (int bb = 0; bb < 4; ++bb) {
            float s = 0.0f;
            #pragma unroll
            for (int q = 0; q < 16; ++q) s += red[((q * 16 + tb) << 2) + bb];
            atomicAdd(&out[(size_t)(bOff + bb) * Tsz + t], s);
        }
    }
}

__global__ void out_init(float* __restrict__ out, const float* __restrict__ b_out, int nElem)
{
    int i = blockIdx.x * blockDim.x + threadIdx.x;
    if (i < nElem) out[i] = b_out[0];
}

extern "C" void kernel_launch(void* const* d_in, const int* in_sizes, int n_in,
                              void* d_out, int out_size, void* d_ws, size_t ws_size,
                              hipStream_t stream)
{
    const float* x     = (const float*)d_in[0];
    const float* W_ih1 = (const float*)d_in[1];
    const float* W_hh1 = (const float*)d_in[2];
    const float* b_ih1 = (const float*)d_in[3];
    const float* b_hh1 = (const float*)d_in[4];
    const float* W_ih2 = (const float*)d_in[5];
    const float* W_hh2 = (const float*)d_in[6];
    const float* b_ih2 = (const float*)d_in[7];
    const float* b_hh2 = (const float*)d_in[8];
    const float* W_out = (const float*)d_in[9];
    const float* b_out = (const float*)d_in[10];
    // d_in[11] = future (static 0) — ignored

    float* out = (float*)d_out;
    float* ws  = (float*)d_ws;

    const int S = Hsz * Bsz;           // 262144 floats per state buffer
    float* h1a = ws;                   // [H][B], ping
    float* h2a = ws + (size_t)S;       // [H][B], ping
    float* c1  = ws + (size_t)2 * S;   // in-place
    float* c2  = ws + (size_t)3 * S;   // in-place
    float* h1b = ws + (size_t)4 * S;   // pong
    float* h2b = ws + (size_t)5 * S;   // pong

    // zero initial states (h1a, h2a, c1, c2 are contiguous)
    hipMemsetAsync(ws, 0, (size_t)4 * S * sizeof(float), stream);
    // pre-fill output with b_out (atomics accumulate the h2.W_out partials)
    out_init<<<dim3((Bsz * Tsz + 255) / 256), 256, 0, stream>>>(out, b_out, Bsz * Tsz);

    for (int t = 0; t < Tsz; ++t) {
        float* h1_in  = (t & 1) ? h1b : h1a;
        float* h1_out = (t & 1) ? h1a : h1b;
        float* h2_in  = (t & 1) ? h2b : h2a;
        float* h2_out = (t & 1) ? h2a : h2b;
        phaseA<<<dim3(64, 4), 256, 0, stream>>>(h1_in, h1_out, c1, x,
                                                W_ih1, W_hh1, b_ih1, b_hh1, t);
        phaseB<<<dim3(64, 4), 256, 0, stream>>>(h1_out, h2_in, h2_out, c2,
                                                W_ih2, W_hh2, b_ih2, b_hh2,
                                                W_out, out, t);
    }
}

// Round 2
// 66393.030 us; speedup vs baseline: 1.9831x; 1.9831x over previous
//
#include <hip/hip_runtime.h>
#include <math.h>

#define Hsz 1024
#define Bsz 256
#define Tsz 512

using half8 = __attribute__((ext_vector_type(8))) _Float16;
using f32x4 = __attribute__((ext_vector_type(4))) float;

#define MFMA(a, b, c) __builtin_amdgcn_mfma_f32_16x16x32_f16(a, b, c, 0, 0, 0)
#define INV2048 (1.0f / 2048.0f)

__device__ __forceinline__ float sigm(float v)   { return 1.0f / (1.0f + expf(-v)); }
__device__ __forceinline__ float tanh_f(float v) { float e = expf(2.0f * v); return 1.0f - 2.0f / (e + 1.0f); }

// ---------------------------------------------------------------------------
// Phase A: layer-1 cell. gates[n][b] = W_hh1[n][k] @ h1[k][b], n = g*1024+hid.
// Block: 4 waves; wave covers 4 gate-tiles (16x16) x 16 b, full K=1024.
// A-frag: lane reads W[n0 + (lane&15)][k0 + (lane>>4)*8 ..+8]  (16B contig).
// B-frag: lane reads h[b0 + (lane&15)][k0 + (lane>>4)*8 ..+8]  (16B contig).
// C/D: col=lane&15 (b), row=(lane>>4)*4+reg (n) -> all 4 gates of one hidden
// unit land in the same lane & reg index => in-register cell update.
// Split-fp16: x = hi + lo/2048; acc0 = hi*hi; acc1 = hi*lo + lo*hi (x2048).
// ---------------------------------------------------------------------------
__global__ __launch_bounds__(256) void phaseA(
    const _Float16* __restrict__ Whi, const _Float16* __restrict__ Wlo,   // [4096][1024]
    const _Float16* __restrict__ hRhi, const _Float16* __restrict__ hRlo, // read buf [256][2048]
    _Float16* __restrict__ hWhi, _Float16* __restrict__ hWlo,             // write buf [256][2048]
    float* __restrict__ c1, const float* __restrict__ x,
    const float* __restrict__ Wih1, const float* __restrict__ b1, int t)
{
    const int lane = threadIdx.x & 63;
    const int wv   = threadIdx.x >> 6;
    const int m    = lane & 15;
    const int quad = lane >> 4;
    const int h0   = blockIdx.x << 4;
    const int bRow = (blockIdx.y << 6) + (wv << 4) + m;

    const _Float16* pBh  = hRhi + bRow * 2048 + (quad << 3);
    const _Float16* pBl  = hRlo + bRow * 2048 + (quad << 3);
    const _Float16* pAh0 = Whi + ((h0 + m) << 10) + (quad << 3);  // gate g: + (g<<20)
    const _Float16* pAl0 = Wlo + ((h0 + m) << 10) + (quad << 3);

    f32x4 acc0[4], acc1[4];
    #pragma unroll
    for (int g = 0; g < 4; ++g) { acc0[g] = (f32x4){0,0,0,0}; acc1[g] = (f32x4){0,0,0,0}; }

    #pragma unroll 2
    for (int k0 = 0; k0 < 1024; k0 += 32) {
        const half8 bh = *(const half8*)(pBh + k0);
        const half8 bl = *(const half8*)(pBl + k0);
        #pragma unroll
        for (int g = 0; g < 4; ++g) {
            const half8 ah = *(const half8*)(pAh0 + (g << 20) + k0);
            const half8 al = *(const half8*)(pAl0 + (g << 20) + k0);
            acc0[g] = MFMA(ah, bh, acc0[g]);
            acc1[g] = MFMA(ah, bl, acc1[g]);
            acc1[g] = MFMA(al, bh, acc1[g]);
        }
    }

    const float xv = x[bRow * Tsz + t];
    #pragma unroll
    for (int r = 0; r < 4; ++r) {
        const int hid = h0 + (quad << 2) + r;
        const float gi_ = acc0[0][r] + acc1[0][r] * INV2048 + xv * Wih1[hid]        + b1[hid];
        const float gf_ = acc0[1][r] + acc1[1][r] * INV2048 + xv * Wih1[1024 + hid] + b1[1024 + hid];
        const float gg_ = acc0[2][r] + acc1[2][r] * INV2048 + xv * Wih1[2048 + hid] + b1[2048 + hid];
        const float go_ = acc0[3][r] + acc1[3][r] * INV2048 + xv * Wih1[3072 + hid] + b1[3072 + hid];
        const int ci = (hid << 8) + bRow;
        const float cn = sigm(gf_) * c1[ci] + sigm(gi_) * tanh_f(gg_);
        c1[ci] = cn;
        const float hn = sigm(go_) * tanh_f(cn);
        const _Float16 hh = (_Float16)hn;
        hWhi[bRow * 2048 + hid] = hh;
        hWlo[bRow * 2048 + hid] = (_Float16)((hn - (float)hh) * 2048.0f);
    }
}

// ---------------------------------------------------------------------------
// Phase B: layer-2 cell + out projection. K=2048: k<1024 = h1 (current, in
// write buf), k>=1024 = h2 (prev, in read buf). Writes h2 at k-offset 1024.
// ---------------------------------------------------------------------------
__global__ __launch_bounds__(256) void phaseB(
    const _Float16* __restrict__ Whi, const _Float16* __restrict__ Wlo,   // [4096][2048]
    _Float16* hCurHi, _Float16* hCurLo,                                   // h1 read / h2 write
    const _Float16* __restrict__ hPrvHi, const _Float16* __restrict__ hPrvLo,
    float* __restrict__ c2, const float* __restrict__ Wout,
    const float* __restrict__ b2, float* __restrict__ out, int t)
{
    const int lane = threadIdx.x & 63;
    const int wv   = threadIdx.x >> 6;
    const int m    = lane & 15;
    const int quad = lane >> 4;
    const int h0   = blockIdx.x << 4;
    const int bRow = (blockIdx.y << 6) + (wv << 4) + m;

    const _Float16* pAh0 = Whi + (h0 + m) * 2048 + (quad << 3);  // gate g: + (g<<21)
    const _Float16* pAl0 = Wlo + (h0 + m) * 2048 + (quad << 3);
    const int bOff = bRow * 2048 + (quad << 3);

    f32x4 acc0[4], acc1[4];
    #pragma unroll
    for (int g = 0; g < 4; ++g) { acc0[g] = (f32x4){0,0,0,0}; acc1[g] = (f32x4){0,0,0,0}; }

    #pragma unroll 2
    for (int k0 = 0; k0 < 1024; k0 += 32) {      // h1 contribution
        const half8 bh = *(const half8*)(hCurHi + bOff + k0);
        const half8 bl = *(const half8*)(hCurLo + bOff + k0);
        #pragma unroll
        for (int g = 0; g < 4; ++g) {
            const half8 ah = *(const half8*)(pAh0 + (g << 21) + k0);
            const half8 al = *(const half8*)(pAl0 + (g << 21) + k0);
            acc0[g] = MFMA(ah, bh, acc0[g]);
            acc1[g] = MFMA(ah, bl, acc1[g]);
            acc1[g] = MFMA(al, bh, acc1[g]);
        }
    }
    #pragma unroll 2
    for (int k0 = 1024; k0 < 2048; k0 += 32) {   // h2 (prev) contribution
        const half8 bh = *(const half8*)(hPrvHi + bOff + k0);
        const half8 bl = *(const half8*)(hPrvLo + bOff + k0);
        #pragma unroll
        for (int g = 0; g < 4; ++g) {
            const half8 ah = *(const half8*)(pAh0 + (g << 21) + k0);
            const half8 al = *(const half8*)(pAl0 + (g << 21) + k0);
            acc0[g] = MFMA(ah, bh, acc0[g]);
            acc1[g] = MFMA(ah, bl, acc1[g]);
            acc1[g] = MFMA(al, bh, acc1[g]);
        }
    }

    float po = 0.0f;
    #pragma unroll
    for (int r = 0; r < 4; ++r) {
        const int hid = h0 + (quad << 2) + r;
        const float gi_ = acc0[0][r] + acc1[0][r] * INV2048 + b2[hid];
        const float gf_ = acc0[1][r] + acc1[1][r] * INV2048 + b2[1024 + hid];
        const float gg_ = acc0[2][r] + acc1[2][r] * INV2048 + b2[2048 + hid];
        const float go_ = acc0[3][r] + acc1[3][r] * INV2048 + b2[3072 + hid];
        const int ci = (hid << 8) + bRow;
        const float cn = sigm(gf_) * c2[ci] + sigm(gi_) * tanh_f(gg_);
        c2[ci] = cn;
        const float hn = sigm(go_) * tanh_f(cn);
        const _Float16 hh = (_Float16)hn;
        hCurHi[bRow * 2048 + 1024 + hid] = hh;
        hCurLo[bRow * 2048 + 1024 + hid] = (_Float16)((hn - (float)hh) * 2048.0f);
        po += hn * Wout[hid];
    }
    po += __shfl_xor(po, 16);
    po += __shfl_xor(po, 32);
    if (quad == 0) atomicAdd(&out[bRow * Tsz + t], po);
}

// --------------------------- prep kernels ----------------------------------
__global__ void prepA(const float* __restrict__ src, _Float16* __restrict__ hi,
                      _Float16* __restrict__ lo)
{
    for (int i = blockIdx.x * blockDim.x + threadIdx.x; i < 4096 * 1024;
         i += gridDim.x * blockDim.x) {
        float v = src[i];
        _Float16 h = (_Float16)v;
        hi[i] = h;
        lo[i] = (_Float16)((v - (float)h) * 2048.0f);
    }
}

__global__ void prepB(const float* __restrict__ Wih2, const float* __restrict__ Whh2,
                      _Float16* __restrict__ hi, _Float16* __restrict__ lo)
{
    for (int i = blockIdx.x * blockDim.x + threadIdx.x; i < 4096 * 2048;
         i += gridDim.x * blockDim.x) {
        int n = i >> 11, k = i & 2047;
        float v = (k < 1024) ? Wih2[(n << 10) + k] : Whh2[(n << 10) + k - 1024];
        _Float16 h = (_Float16)v;
        hi[i] = h;
        lo[i] = (_Float16)((v - (float)h) * 2048.0f);
    }
}

__global__ void prepBias(const float* a1, const float* c1_, const float* a2,
                         const float* c2_, float* o1, float* o2)
{
    int i = blockIdx.x * blockDim.x + threadIdx.x;
    if (i < 4096) { o1[i] = a1[i] + c1_[i]; o2[i] = a2[i] + c2_[i]; }
}

__global__ void outInit(float* __restrict__ out, const float* __restrict__ b_out)
{
    int i = blockIdx.x * blockDim.x + threadIdx.x;
    if (i < Bsz * Tsz) out[i] = b_out[0];
}

// ---------------------------------------------------------------------------
extern "C" void kernel_launch(void* const* d_in, const int* in_sizes, int n_in,
                              void* d_out, int out_size, void* d_ws, size_t ws_size,
                              hipStream_t stream)
{
    const float* x     = (const float*)d_in[0];
    const float* W_ih1 = (const float*)d_in[1];
    const float* W_hh1 = (const float*)d_in[2];
    const float* b_ih1 = (const float*)d_in[3];
    const float* b_hh1 = (const float*)d_in[4];
    const float* W_ih2 = (const float*)d_in[5];
    const float* W_hh2 = (const float*)d_in[6];
    const float* b_ih2 = (const float*)d_in[7];
    const float* b_hh2 = (const float*)d_in[8];
    const float* W_out = (const float*)d_in[9];
    const float* b_out = (const float*)d_in[10];

    char* ws = (char*)d_ws;
    const size_t MB = 1 << 20;
    _Float16* WAhi    = (_Float16*)(ws);            //  8 MB  [4096][1024]
    _Float16* WAlo    = (_Float16*)(ws + 8 * MB);   //  8 MB
    _Float16* W2hi    = (_Float16*)(ws + 16 * MB);  // 16 MB  [4096][2048]
    _Float16* W2lo    = (_Float16*)(ws + 32 * MB);  // 16 MB
    float*    c1      = (float*)(ws + 48 * MB);     //  1 MB  [1024][256]
    float*    c2      = (float*)(ws + 49 * MB);     //  1 MB
    _Float16* hPingHi = (_Float16*)(ws + 50 * MB);  //  1 MB  [256][2048]
    _Float16* hPingLo = (_Float16*)(ws + 51 * MB);
    _Float16* hPongHi = (_Float16*)(ws + 52 * MB);
    _Float16* hPongLo = (_Float16*)(ws + 53 * MB);
    float*    b1      = (float*)(ws + 54 * MB);
    float*    b2      = (float*)(ws + 54 * MB + 16384);

    // zero c1, c2, ping(hi,lo) in one contiguous memset
    hipMemsetAsync(ws + 48 * MB, 0, 4 * MB, stream);
    prepA<<<1024, 256, 0, stream>>>(W_hh1, WAhi, WAlo);
    prepB<<<2048, 256, 0, stream>>>(W_ih2, W_hh2, W2hi, W2lo);
    prepBias<<<16, 256, 0, stream>>>(b_ih1, b_hh1, b_ih2, b_hh2, b1, b2);
    outInit<<<512, 256, 0, stream>>>((float*)d_out, b_out);

    for (int t = 0; t < Tsz; ++t) {
        _Float16* rHi = (t & 1) ? hPongHi : hPingHi;
        _Float16* rLo = (t & 1) ? hPongLo : hPingLo;
        _Float16* wHi = (t & 1) ? hPingHi : hPongHi;
        _Float16* wLo = (t & 1) ? hPingLo : hPongLo;
        phaseA<<<dim3(64, 4), 256, 0, stream>>>(WAhi, WAlo, rHi, rLo, wHi, wLo,
                                                c1, x, W_ih1, b1, t);
        phaseB<<<dim3(64, 4), 256, 0, stream>>>(W2hi, W2lo, wHi, wLo, rHi, rLo,
                                                c2, W_out, b2, (float*)d_out, t);
    }
}